// Round 9
// baseline (131.429 us; speedup 1.0000x reference)
//
#include <hip/hip_runtime.h>
#include <hip/hip_bf16.h>

#define B_ROWS 16384
#define D_DIM  1024
#define F_DIM  1031
#define KP     1088   // padded K (17 * 64)
#define NP     1152   // padded N / hidden stride (9 * 128)
#define NT_N   9
#define NT_M   128

typedef __attribute__((ext_vector_type(4))) float  f32x4;
typedef __attribute__((ext_vector_type(8))) short  bf16x8;

__device__ __forceinline__ unsigned short f2bf(float f) {
    unsigned int x = __float_as_uint(f);
    unsigned int r = (x + 0x7fffu + ((x >> 16) & 1u)) >> 16;
    return (unsigned short)r;
}
__device__ __forceinline__ float bf2f(unsigned short u) {
    return __uint_as_float((unsigned int)u << 16);
}
__device__ __forceinline__ void gload16(const void* g, void* l) {
    __builtin_amdgcn_global_load_lds(
        (const __attribute__((address_space(1))) void*)g,
        (__attribute__((address_space(3))) void*)l, 16, 0, 0);
}

// ---------------- Kernel 1: per-row reductions + bf16 feature rows (1 wave = 1 row) ----
// No LDS, no barriers, no serial section: 64-lane butterfly reduce; every lane ends
// with the row totals and computes the scalar features redundantly.
__global__ __launch_bounds__(256) void k_features(
        const float* __restrict__ h, const float* __restrict__ vc,
        const float* __restrict__ vb, unsigned short* __restrict__ featpad) {
    int tid  = threadIdx.x;
    int lane = tid & 63;
    int row  = blockIdx.x * 4 + (tid >> 6);

    const float4* h4 = (const float4*)(h  + (size_t)row * D_DIM);
    const float4* c4 = (const float4*)(vc + (size_t)row * D_DIM);
    const float4* b4 = (const float4*)(vb + (size_t)row * D_DIM);

    // lane loads float4 blocks lane + 64*b  (b = 0..3) from each array
    float4 hv[4], cv[4], bv[4];
    #pragma unroll
    for (int b = 0; b < 4; ++b) {
        hv[b] = h4[lane + 64 * b];
        cv[b] = c4[lane + 64 * b];
        bv[b] = b4[lane + 64 * b];
    }

    float nc = 0.f, nb = 0.f, dcb = 0.f, nh = 0.f;
    #pragma unroll
    for (int b = 0; b < 4; ++b) {
        nc  += cv[b].x*cv[b].x + cv[b].y*cv[b].y + cv[b].z*cv[b].z + cv[b].w*cv[b].w;
        nb  += bv[b].x*bv[b].x + bv[b].y*bv[b].y + bv[b].z*bv[b].z + bv[b].w*bv[b].w;
        dcb += cv[b].x*bv[b].x + cv[b].y*bv[b].y + cv[b].z*bv[b].z + cv[b].w*bv[b].w;
        nh  += hv[b].x*hv[b].x + hv[b].y*hv[b].y + hv[b].z*hv[b].z + hv[b].w*hv[b].w;
    }
    #pragma unroll
    for (int o = 1; o < 64; o <<= 1) {
        nc  += __shfl_xor(nc,  o);
        nb  += __shfl_xor(nb,  o);
        dcb += __shfl_xor(dcb, o);
        nh  += __shfl_xor(nh,  o);
    }

    // all lanes: scalar features (redundant, cheap)
    float rc = sqrtf(nc), rb = sqrtf(nb), rh = sqrtf(nh);
    float mc = fmaxf(rc, 1e-12f), mb = fmaxf(rb, 1e-12f);
    float align = dcb / (mc * mb);
    float t2 = nc/(mc*mc) - 2.f*dcb/(mc*mb) + nb/(mb*mb);
    t2 = fmaxf(t2, 0.f);
    float scal[8];
    scal[0] = align;
    scal[1] = sqrtf(t2);
    scal[2] = t2;
    scal[3] = sqrtf(fmaxf(nc - 2.f*dcb + nb, 0.f));
    scal[4] = rc; scal[5] = rb; scal[6] = rh; scal[7] = 0.f;

    unsigned short* orow = featpad + (size_t)row * KP;
    // main: lane writes its 4 held float4 blocks as bf16 uint2 (coalesced per b)
    #pragma unroll
    for (int b = 0; b < 4; ++b) {
        union { unsigned int u[2]; unsigned short us[4]; } w;
        w.us[0] = f2bf(hv[b].x); w.us[1] = f2bf(hv[b].y);
        w.us[2] = f2bf(hv[b].z); w.us[3] = f2bf(hv[b].w);
        *(uint2*)(orow + 4 * (lane + 64 * b)) = *(uint2*)w.u;
    }
    // tail: columns 1024..1087 (7 scalars + zeros), 8 lanes x 8 bf16
    if (lane < 8) {
        union { uint4 v; unsigned short us[8]; } pack;
        #pragma unroll
        for (int i = 0; i < 8; ++i) {
            int sc = 1024 + lane * 8 + i;
            pack.us[i] = f2bf((sc < F_DIM) ? scal[sc - D_DIM] : 0.f);
        }
        *(uint4*)(orow + 1024 + lane * 8) = pack.v;
    }
}

// ---------------- Kernel 2: W1 -> W1^T bf16, padded, linear ----------------
__global__ __launch_bounds__(256) void k_w1t(const float* __restrict__ W1,
                                             unsigned short* __restrict__ w1t) {
    int idx = blockIdx.x * 256 + threadIdx.x;
    if (idx >= NP * KP) return;
    int n = idx / KP, c = idx % KP;
    float v = 0.f;
    if (n < F_DIM && c < F_DIM) v = W1[(size_t)c * F_DIM + n];
    w1t[idx] = f2bf(v);
}

// ---------------- Kernel 3: GEMM1 (+b1, ReLU) -> bf16 hidden (m97 structure) ----------
__global__ __launch_bounds__(256, 1) void k_gemm(
        const unsigned short* __restrict__ A,   // featpad [16384][1088]
        const unsigned short* __restrict__ Bt,  // w1t [1152][1088]
        const float* __restrict__ b1,
        unsigned short* __restrict__ hidden) {  // [16384][1152]
    __shared__ unsigned short As[128 * 64];   // 16 KB, linear
    __shared__ unsigned short Bs[128 * 64];   // 16 KB, linear
    __shared__ float b1s[128];

    int tid = threadIdx.x;
    int lane = tid & 63;
    int wid = tid >> 6;

    // XCD-aware mapping (bijective): 9 nt-blocks per A panel on one XCD.
    int id = blockIdx.x;            // 0..1151
    int xcd = id & 7;
    int slot = id >> 3;             // 0..143
    int mt = xcd * 16 + slot / NT_N;
    int nt = slot % NT_N;

    if (tid < 128) {
        int ncol = nt * 128 + tid;
        b1s[tid] = (ncol < F_DIM) ? b1[ncol] : 0.f;
    }

    f32x4 acc[4][4] = {};
    int wm = wid >> 1, wn = wid & 1;

    const unsigned short* aSrc = A  + ((size_t)(mt * 128 + wid * 32 + (lane >> 3))) * KP + (lane & 7) * 8;
    const unsigned short* bSrc = Bt + ((size_t)(nt * 128 + wid * 32 + (lane >> 3))) * KP + (lane & 7) * 8;
    unsigned short* aDst = As + wid * 32 * 64;
    unsigned short* bDst = Bs + wid * 32 * 64;

    for (int kt = 0; kt < KP / 64; ++kt) {
        __syncthreads();
        #pragma unroll
        for (int i = 0; i < 4; ++i) {
            gload16(aSrc + kt * 64 + (size_t)i * 8 * KP, aDst + i * 8 * 64);
            gload16(bSrc + kt * 64 + (size_t)i * 8 * KP, bDst + i * 8 * 64);
        }
        __syncthreads();
        #pragma unroll
        for (int kk = 0; kk < 2; ++kk) {
            bf16x8 af[4], bfr[4];
            int klane = kk * 32 + ((lane >> 4) << 3);
            #pragma unroll
            for (int m = 0; m < 4; ++m) {
                int arow = wm * 64 + m * 16 + (lane & 15);
                af[m] = *(const bf16x8*)&As[arow * 64 + klane];
            }
            #pragma unroll
            for (int n = 0; n < 4; ++n) {
                int brow = wn * 64 + n * 16 + (lane & 15);
                bfr[n] = *(const bf16x8*)&Bs[brow * 64 + klane];
            }
            #pragma unroll
            for (int m = 0; m < 4; ++m)
                #pragma unroll
                for (int n = 0; n < 4; ++n)
                    acc[m][n] = __builtin_amdgcn_mfma_f32_16x16x32_bf16(af[m], bfr[n], acc[m][n], 0, 0, 0);
        }
    }

    #pragma unroll
    for (int m = 0; m < 4; ++m) {
        #pragma unroll
        for (int n = 0; n < 4; ++n) {
            int coll = wn * 64 + n * 16 + (lane & 15);
            int col = nt * 128 + coll;
            #pragma unroll
            for (int r = 0; r < 4; ++r) {
                int row = mt * 128 + wm * 64 + m * 16 + ((lane >> 4) << 2) + r;
                float v = acc[m][n][r] + b1s[coll];
                hidden[(size_t)row * NP + col] = f2bf(fmaxf(v, 0.f));
            }
        }
    }
}

// ---------------- Kernel 4: out = hidden @ W2 + b2 (memory-bound stream) -------------
__global__ __launch_bounds__(256) void k_head(const unsigned short* __restrict__ hidden,
                                              const float* __restrict__ W2,
                                              const float* __restrict__ b2,
                                              float* __restrict__ out) {
    __shared__ float W2s[NP * 5];   // 23,040 B
    int tid = threadIdx.x;
    for (int idx = tid; idx < NP * 5; idx += 256) {
        int n = idx / 5, j = idx % 5;
        W2s[idx] = (n < F_DIM) ? W2[n * 5 + j] : 0.f;
    }
    __syncthreads();

    int wid = tid >> 6, lane = tid & 63;
    int row = blockIdx.x * 16 + wid * 4 + (lane >> 4);   // 16 rows/block
    int seg = lane & 15;                                  // 16 lanes per row, 72 cols each
    const unsigned short* hr = hidden + (size_t)row * NP + seg * 72;

    float s[5] = {0.f, 0.f, 0.f, 0.f, 0.f};
    #pragma unroll
    for (int c = 0; c < 9; ++c) {
        union { uint4 v; unsigned short us[8]; } pk;
        pk.v = *(const uint4*)(hr + c * 8);
        #pragma unroll
        for (int e = 0; e < 8; ++e) {
            float hv = bf2f(pk.us[e]);
            int col = seg * 72 + c * 8 + e;
            #pragma unroll
            for (int j = 0; j < 5; ++j) s[j] += hv * W2s[col * 5 + j];
        }
    }
    #pragma unroll
    for (int o = 1; o < 16; o <<= 1) {
        #pragma unroll
        for (int j = 0; j < 5; ++j) s[j] += __shfl_xor(s[j], o);
    }
    if (seg == 0) {
        #pragma unroll
        for (int j = 0; j < 5; ++j) out[(size_t)row * 5 + j] = s[j] + b2[j];
    }
}

extern "C" void kernel_launch(void* const* d_in, const int* in_sizes, int n_in,
                              void* d_out, int out_size, void* d_ws, size_t ws_size,
                              hipStream_t stream) {
    const float* h_final   = (const float*)d_in[0];
    const float* v_current = (const float*)d_in[1];
    const float* v_basin   = (const float*)d_in[2];
    const float* W1        = (const float*)d_in[3];
    const float* b1        = (const float*)d_in[4];
    const float* W2        = (const float*)d_in[5];
    const float* b2        = (const float*)d_in[6];
    float* out = (float*)d_out;

    char* ws = (char*)d_ws;
    unsigned short* featpad = (unsigned short*)ws;                       // 16384*1088*2 = 35,651,584 B
    unsigned short* w1t     = (unsigned short*)(ws + 35651584);          // 1152*1088*2  =  2,506,752 B
    unsigned short* hidden  = (unsigned short*)(ws + 35651584 + 2506752);// 16384*1152*2 = 37,748,736 B

    k_features<<<dim3(B_ROWS / 4), dim3(256), 0, stream>>>(h_final, v_current, v_basin, featpad);
    k_w1t<<<dim3((NP * KP + 255) / 256), dim3(256), 0, stream>>>(W1, w1t);
    k_gemm<<<dim3(NT_N * NT_M), dim3(256), 0, stream>>>(featpad, w1t, b1, hidden);
    k_head<<<dim3(B_ROWS / 16), dim3(256), 0, stream>>>(hidden, W2, b2, out);
}